// Round 1
// baseline (519.959 us; speedup 1.0000x reference)
//
#include <hip/hip_runtime.h>

#define BINS 25
#define KS 7
#define PAD 3
#define H 512
#define W 512
#define OH 256
#define OW 256
#define NPLANES 96   // B*C = 32*3

// binomial row [1,6,15,20,15,6,1]/64
__device__ __forceinline__ float pascal_row(int i) {
    const float r[KS] = {1.f/64.f, 6.f/64.f, 15.f/64.f, 20.f/64.f, 15.f/64.f, 6.f/64.f, 1.f/64.f};
    return r[i];
}

__global__ void zero_hist(unsigned int* h, int n) {
    int i = blockIdx.x * blockDim.x + threadIdx.x;
    if (i < n) h[i] = 0u;
}

// One thread per output pixel. blockDim = (16,16). gridDim = (OW/16, OH/16, 2*NPLANES).
// z < NPLANES -> x tensor, else y tensor.
__global__ void blur_hist(const float* __restrict__ x, const float* __restrict__ y,
                          unsigned int* __restrict__ hx, unsigned int* __restrict__ hy) {
    int z = blockIdx.z;
    const float* src;
    unsigned int* hist;
    int p;
    if (z < NPLANES) { src = x; hist = hx; p = z; }
    else             { src = y; hist = hy; p = z - NPLANES; }
    src  += (size_t)p * H * W;
    hist += p * BINS;

    __shared__ unsigned int sh[BINS];
    int tid = threadIdx.y * 16 + threadIdx.x;
    if (tid < BINS) sh[tid] = 0u;
    __syncthreads();

    int ox = blockIdx.x * 16 + threadIdx.x;
    int oy = blockIdx.y * 16 + threadIdx.y;

    int iy0 = 2 * oy - PAD;
    int ix0 = 2 * ox - PAD;
    float acc = 0.f;
    #pragma unroll
    for (int ky = 0; ky < KS; ky++) {
        int iy = iy0 + ky;
        if (iy < 0 || iy >= H) continue;
        const float* rowp = src + (size_t)iy * W;
        float racc = 0.f;
        #pragma unroll
        for (int kx = 0; kx < KS; kx++) {
            int ix = ix0 + kx;
            if (ix < 0 || ix >= W) continue;
            racc += pascal_row(kx) * rowp[ix];
        }
        acc += pascal_row(ky) * racc;
    }

    // histc semantics: bins over [0,1], outside ignored, v==1 -> last bin
    if (acc >= 0.f && acc <= 1.f) {
        int idx = (int)floorf(acc * (float)BINS);
        idx = min(max(idx, 0), BINS - 1);
        atomicAdd(&sh[idx], 1u);
    }
    __syncthreads();
    if (tid < BINS && sh[tid] != 0u) atomicAdd(&hist[tid], sh[tid]);
}

// Single block of 128 threads: 96 cosine sims + mean.
__global__ void reduce_cos(const unsigned int* __restrict__ hx,
                           const unsigned int* __restrict__ hy,
                           float* __restrict__ out) {
    const float inv_hw = 1.0f / (float)(H * W);
    int t = threadIdx.x;
    float c = 0.f;
    if (t < NPLANES) {
        float dot = 0.f, nx = 0.f, ny = 0.f;
        #pragma unroll
        for (int i = 0; i < BINS; i++) {
            float a = (float)hx[t * BINS + i] * inv_hw;
            float b = (float)hy[t * BINS + i] * inv_hw;
            dot += a * b;
            nx  += a * a;
            ny  += b * b;
        }
        nx = fmaxf(sqrtf(nx), 1e-6f);
        ny = fmaxf(sqrtf(ny), 1e-6f);
        c = dot / (nx * ny);
    }
    __shared__ float s[128];
    s[t] = c;
    __syncthreads();
    for (int off = 64; off > 0; off >>= 1) {
        if (t < off) s[t] += s[t + off];
        __syncthreads();
    }
    if (t == 0) out[0] = s[0] / (float)NPLANES;
}

extern "C" void kernel_launch(void* const* d_in, const int* in_sizes, int n_in,
                              void* d_out, int out_size, void* d_ws, size_t ws_size,
                              hipStream_t stream) {
    const float* x = (const float*)d_in[0];
    const float* y = (const float*)d_in[1];
    float* out = (float*)d_out;

    unsigned int* hx = (unsigned int*)d_ws;
    unsigned int* hy = hx + NPLANES * BINS;
    int nhist = 2 * NPLANES * BINS;

    zero_hist<<<(nhist + 255) / 256, 256, 0, stream>>>(hx, nhist);

    dim3 blk(16, 16);
    dim3 grd(OW / 16, OH / 16, 2 * NPLANES);
    blur_hist<<<grd, blk, 0, stream>>>(x, y, hx, hy);

    reduce_cos<<<1, 128, 0, stream>>>(hx, hy, out);
}

// Round 2
// 232.255 us; speedup vs baseline: 2.2387x; 2.2387x over previous
//
#include <hip/hip_runtime.h>

#define BINS 25
#define KS 7
#define H 512
#define W 512
#define OH 256
#define OW 256
#define NPLANES 96   // B*C = 32*3
#define TOX 32       // output tile width
#define TOY 32       // output tile height
#define TIN 69       // input tile rows/cols needed: 2*32 + 7 - 2
#define LDW 72       // floats loaded per row (vec4-aligned cover of 69 needed)
#define TP 76        // LDS pitch of raw tile (floats)
#define HP 33        // LDS pitch of horizontal-result tile (floats)

__global__ void zero_hist(unsigned int* h, int n) {
    int i = blockIdx.x * blockDim.x + threadIdx.x;
    if (i < n) h[i] = 0u;
}

// Block = 256 threads, computes a 32x32 output tile of one plane.
// grid = (OW/TOX, OH/TOY, 2*NPLANES); z < NPLANES -> x tensor, else y.
__global__ __launch_bounds__(256) void blur_hist(
        const float* __restrict__ x, const float* __restrict__ y,
        unsigned int* __restrict__ hx, unsigned int* __restrict__ hy) {
    int z = blockIdx.z;
    const float* src;
    unsigned int* hist;
    if (z < NPLANES) { src = x + (size_t)z * H * W;              hist = hx + z * BINS; }
    else             { src = y + (size_t)(z - NPLANES) * H * W;  hist = hy + (z - NPLANES) * BINS; }

    __shared__ __align__(16) float raw[TIN * TP];   // input tile
    __shared__ float hrz[TIN * HP];                 // horizontal-blur result
    __shared__ unsigned int sh[4 * 32];             // per-wave sub-histograms

    const int tid = threadIdx.x;
    const int ox0 = blockIdx.x * TOX;
    const int oy0 = blockIdx.y * TOY;
    const int base_x = 2 * ox0 - 4;   // tile col t <-> global x = base_x + t
    const int base_y = 2 * oy0 - 3;   // tile row r <-> global y = base_y + r

    if (tid < 128) sh[tid] = 0u;

    // ---- Stage 1: global -> LDS, coalesced float4 ----
    const bool xfull = (base_x >= 0) && (base_x + LDW <= W);
    for (int v = tid; v < TIN * (LDW / 4); v += 256) {
        int r  = v / (LDW / 4);
        int c4 = v - r * (LDW / 4);
        int gy = base_y + r;
        int gx = base_x + 4 * c4;
        float4 val = make_float4(0.f, 0.f, 0.f, 0.f);
        if (gy >= 0 && gy < H) {
            if (xfull) {
                val = *(const float4*)(src + (size_t)gy * W + gx);
            } else {
                const size_t rowb = (size_t)gy * W;
                if (gx + 0 >= 0 && gx + 0 < W) val.x = src[rowb + gx + 0];
                if (gx + 1 >= 0 && gx + 1 < W) val.y = src[rowb + gx + 1];
                if (gx + 2 >= 0 && gx + 2 < W) val.z = src[rowb + gx + 2];
                if (gx + 3 >= 0 && gx + 3 < W) val.w = src[rowb + gx + 3];
            }
        }
        *(float4*)(raw + r * TP + 4 * c4) = val;   // (304r + 16c4) bytes: 16B aligned
    }
    __syncthreads();

    const float w0 = 1.f/64.f, w1 = 6.f/64.f, w2 = 15.f/64.f, w3 = 20.f/64.f;

    // ---- Stage 2: horizontal 7-tap, stride 2 in x; 69 rows x 32 cols ----
    for (int o = tid; o < TIN * TOX; o += 256) {
        int r  = o >> 5;        // 0..68
        int lx = o & 31;        // 0..31
        const float* p = raw + r * TP + 2 * lx + 1;  // tap cols 2lx+1 .. 2lx+7
        float s = w0 * (p[0] + p[6]) + w1 * (p[1] + p[5]) + w2 * (p[2] + p[4]) + w3 * p[3];
        hrz[r * HP + lx] = s;
    }
    __syncthreads();

    // ---- Stage 3: vertical 7-tap, stride 2 in y; 32x32 outputs, 4/thread + hist ----
    const int lx  = tid & 31;
    const int ly0 = (tid >> 5) & 7;
    unsigned int* wh = &sh[(tid >> 6) * 32];
    #pragma unroll
    for (int i = 0; i < 4; i++) {
        int ly = ly0 + 8 * i;
        const float* p = hrz + (2 * ly) * HP + lx;   // tap rows 2ly .. 2ly+6
        float s = w0 * (p[0] + p[6 * HP]) + w1 * (p[1 * HP] + p[5 * HP])
                + w2 * (p[2 * HP] + p[4 * HP]) + w3 * p[3 * HP];
        if (s >= 0.f && s <= 1.f) {
            int b = (int)(s * 25.f);       // trunc == floor for s >= 0
            b = min(b, BINS - 1);
            atomicAdd(&wh[b], 1u);
        }
    }
    __syncthreads();

    if (tid < BINS) {
        unsigned int t = sh[tid] + sh[32 + tid] + sh[64 + tid] + sh[96 + tid];
        if (t) atomicAdd(&hist[tid], t);
    }
}

// Single block of 128 threads: 96 cosine sims + mean.
__global__ void reduce_cos(const unsigned int* __restrict__ hx,
                           const unsigned int* __restrict__ hy,
                           float* __restrict__ out) {
    const float inv_hw = 1.0f / (float)(H * W);
    int t = threadIdx.x;
    float c = 0.f;
    if (t < NPLANES) {
        float dot = 0.f, nx = 0.f, ny = 0.f;
        #pragma unroll
        for (int i = 0; i < BINS; i++) {
            float a = (float)hx[t * BINS + i] * inv_hw;
            float b = (float)hy[t * BINS + i] * inv_hw;
            dot += a * b;
            nx  += a * a;
            ny  += b * b;
        }
        nx = fmaxf(sqrtf(nx), 1e-6f);
        ny = fmaxf(sqrtf(ny), 1e-6f);
        c = dot / (nx * ny);
    }
    __shared__ float s[128];
    s[t] = c;
    __syncthreads();
    for (int off = 64; off > 0; off >>= 1) {
        if (t < off) s[t] += s[t + off];
        __syncthreads();
    }
    if (t == 0) out[0] = s[0] / (float)NPLANES;
}

extern "C" void kernel_launch(void* const* d_in, const int* in_sizes, int n_in,
                              void* d_out, int out_size, void* d_ws, size_t ws_size,
                              hipStream_t stream) {
    const float* x = (const float*)d_in[0];
    const float* y = (const float*)d_in[1];
    float* out = (float*)d_out;

    unsigned int* hx = (unsigned int*)d_ws;
    unsigned int* hy = hx + NPLANES * BINS;
    int nhist = 2 * NPLANES * BINS;

    zero_hist<<<(nhist + 255) / 256, 256, 0, stream>>>(hx, nhist);

    dim3 blk(256);
    dim3 grd(OW / TOX, OH / TOY, 2 * NPLANES);
    blur_hist<<<grd, blk, 0, stream>>>(x, y, hx, hy);

    reduce_cos<<<1, 128, 0, stream>>>(hx, hy, out);
}

// Round 3
// 232.204 us; speedup vs baseline: 2.2392x; 1.0002x over previous
//
#include <hip/hip_runtime.h>

#define BINS 25
#define H 512
#define W 512
#define OH 256
#define OW 256
#define NPLANES 96   // B*C = 32*3
#define TOX 32       // output tile width
#define TOY 16       // output tile height
#define NBX 8        // OW/TOX
#define NBY 16       // OH/TOY
#define NBLK (NBX*NBY)   // 128 blocks per plane
#define TROWS 37     // input rows needed: 2*16+5
#define LDW 72       // floats loaded per row (float4-aligned cover of cols t=0..69)
#define RP 72        // raw tile pitch (floats)
#define VP 36        // ve/vo pitch (floats)
#define NPAIR 35     // column pairs in vertical stage (covers t=0..69)

// Block = 256 threads, one 32x16 output tile of one plane.
// grid = (NBX, NBY, 2*NPLANES); z < NPLANES -> x tensor, else y.
__global__ __launch_bounds__(256) void blur_hist(
        const float* __restrict__ x, const float* __restrict__ y,
        unsigned int* __restrict__ partial) {
    const int z = blockIdx.z;
    const float* src = (z < NPLANES) ? x + (size_t)z * H * W
                                     : y + (size_t)(z - NPLANES) * H * W;

    __shared__ __align__(16) float raw[TROWS * RP];  // 10.65 KB
    __shared__ float ve[TOY * VP];                   // even input cols, vertically blurred
    __shared__ float vo[TOY * VP];                   // odd  input cols, vertically blurred
    __shared__ unsigned int sh[4 * 32];              // per-wave sub-histograms

    const int tid = threadIdx.x;
    const int base_x = 2 * (blockIdx.x * TOX) - 4;   // even; tile col t <-> gx = base_x + t
    const int base_y = 2 * (blockIdx.y * TOY) - 3;   // tile row r <-> gy = base_y + r

    if (tid < 128) sh[tid] = 0u;

    // ---- Stage 1: global -> LDS, coalesced float4 (conflict-free writes) ----
    const bool xfull = (base_x >= 0) && (base_x + LDW <= W);
    for (int v = tid; v < TROWS * (LDW / 4); v += 256) {
        int r  = v / (LDW / 4);
        int c4 = v - r * (LDW / 4);
        int gy = base_y + r;
        int gx = base_x + 4 * c4;
        float4 val = make_float4(0.f, 0.f, 0.f, 0.f);
        if (gy >= 0 && gy < H) {
            if (xfull) {
                val = *(const float4*)(src + (size_t)gy * W + gx);
            } else {
                const size_t rb = (size_t)gy * W;
                if (gx + 0 >= 0 && gx + 0 < W) val.x = src[rb + gx + 0];
                if (gx + 1 >= 0 && gx + 1 < W) val.y = src[rb + gx + 1];
                if (gx + 2 >= 0 && gx + 2 < W) val.z = src[rb + gx + 2];
                if (gx + 3 >= 0 && gx + 3 < W) val.w = src[rb + gx + 3];
            }
        }
        *(float4*)(raw + r * RP + 4 * c4) = val;
    }
    __syncthreads();

    const float w0 = 1.f/64.f, w1 = 6.f/64.f, w2 = 15.f/64.f, w3 = 20.f/64.f;

    // ---- Stage 2: vertical 7-tap (stride 2 in y), two adjacent cols per thread
    //      via float2 reads (lane-contiguous addresses -> conflict-free).
    //      De-interleave result into ve (even t) / vo (odd t). ----
    for (int v = tid; v < TOY * NPAIR; v += 256) {
        int ly = v / NPAIR;
        int pr = v - ly * NPAIR;                    // t = 2*pr (even), 2*pr+1 (odd)
        const float2* p = (const float2*)(raw + 2 * ly * RP + 2 * pr);
        float2 a0 = p[0 * (RP/2)], a1 = p[1 * (RP/2)], a2 = p[2 * (RP/2)],
               a3 = p[3 * (RP/2)], a4 = p[4 * (RP/2)], a5 = p[5 * (RP/2)],
               a6 = p[6 * (RP/2)];
        ve[ly * VP + pr] = w0*(a0.x+a6.x) + w1*(a1.x+a5.x) + w2*(a2.x+a4.x) + w3*a3.x;
        vo[ly * VP + pr] = w0*(a0.y+a6.y) + w1*(a1.y+a5.y) + w2*(a2.y+a4.y) + w3*a3.y;
    }
    __syncthreads();

    // ---- Stage 3: horizontal 7-tap (stride 2 in x) from de-interleaved arrays
    //      (stride-1 reads -> conflict-free) + histogram. 2 outputs/thread. ----
    const int lx = tid & 31;
    unsigned int* wh = &sh[(tid >> 6) * 32];
    #pragma unroll
    for (int i = 0; i < 2; i++) {
        int ly = (tid >> 5) + 8 * i;
        const float* e = ve + ly * VP + lx;
        const float* o = vo + ly * VP + lx;
        // taps t=2lx+1..2lx+7: odd -> o[lx..lx+3] (w0,w2,w2,w0), even -> e[lx+1..lx+3] (w1,w3,w1)
        float s = w0*(o[0] + o[3]) + w2*(o[1] + o[2]) + w1*(e[1] + e[3]) + w3*e[2];
        int b = min((int)(s * 25.f), BINS - 1);     // s in [0,1] by construction
        atomicAdd(&wh[b], 1u);
    }
    __syncthreads();

    // ---- Per-block histogram write-out (no global atomics, no pre-zeroing) ----
    if (tid < BINS) {
        unsigned int t = sh[tid] + sh[32 + tid] + sh[64 + tid] + sh[96 + tid];
        int blk = blockIdx.y * NBX + blockIdx.x;
        partial[((size_t)z * NBLK + blk) * BINS + tid] = t;
    }
}

// 96 blocks x 256 threads: block p reduces plane p's partials for x and y,
// computes cosine sim, atomically accumulates mean into out[0].
__global__ __launch_bounds__(256) void reduce_cos(
        const unsigned int* __restrict__ partial, float* __restrict__ out) {
    __shared__ unsigned int sh[2 * BINS];
    const int p = blockIdx.x;
    const int t = threadIdx.x;
    if (t < 2 * BINS) sh[t] = 0u;
    __syncthreads();
    const unsigned int* xp = partial + (size_t)p * NBLK * BINS;
    const unsigned int* yp = partial + (size_t)(NPLANES + p) * NBLK * BINS;
    for (int f = t; f < NBLK * BINS; f += 256) {
        int b = f % BINS;
        atomicAdd(&sh[b], xp[f]);
        atomicAdd(&sh[BINS + b], yp[f]);
    }
    __syncthreads();
    if (t == 0) {
        const float inv_hw = 1.0f / (float)(H * W);
        float dot = 0.f, nx = 0.f, ny = 0.f;
        for (int i = 0; i < BINS; i++) {
            float a = (float)sh[i] * inv_hw;
            float b = (float)sh[BINS + i] * inv_hw;
            dot += a * b;
            nx  += a * a;
            ny  += b * b;
        }
        nx = fmaxf(sqrtf(nx), 1e-6f);
        ny = fmaxf(sqrtf(ny), 1e-6f);
        atomicAdd(out, (dot / (nx * ny)) * (1.0f / (float)NPLANES));
    }
}

extern "C" void kernel_launch(void* const* d_in, const int* in_sizes, int n_in,
                              void* d_out, int out_size, void* d_ws, size_t ws_size,
                              hipStream_t stream) {
    const float* x = (const float*)d_in[0];
    const float* y = (const float*)d_in[1];
    float* out = (float*)d_out;

    // partial hists: [2*NPLANES][NBLK][BINS] uint = 192*128*25*4 = 2.46 MB in ws.
    unsigned int* partial = (unsigned int*)d_ws;

    hipMemsetAsync(out, 0, sizeof(float), stream);  // memset node: zero the accumulator

    dim3 grd(NBX, NBY, 2 * NPLANES);
    blur_hist<<<grd, 256, 0, stream>>>(x, y, partial);

    reduce_cos<<<NPLANES, 256, 0, stream>>>(partial, out);
}

// Round 4
// 231.567 us; speedup vs baseline: 2.2454x; 1.0028x over previous
//
#include <hip/hip_runtime.h>

#define BINS 25
#define H 512
#define W 512
#define NPLANES 96   // B*C = 32*3
#define TOX 32       // output tile width
#define TOY 16       // output tile height
#define NBX 8        // OW/TOX
#define NBY 16       // OH/TOY
#define NBLK (NBX*NBY)   // 128 tiles per plane
#define TROWS 37     // input rows: 2*16+5
#define RP 72        // raw pitch (floats) = 18 float4 -> contiguous lane mapping for async LDS
#define NV4 (TROWS*18)   // 666 float4 loads per tile
#define VP 36        // ve/vo pitch
#define NSH 32       // sub-histograms per block

__device__ __forceinline__ void async_load16(const float* g, float* lds_wave_base) {
    // HW semantics: LDS dest = wave-uniform base + lane*16 (m104/m108); 16B verified (m97).
    __builtin_amdgcn_global_load_lds(
        (const __attribute__((address_space(1))) void*)g,
        (__attribute__((address_space(3))) void*)lds_wave_base,
        16, 0, 0);
}

// Block = 256 threads, one 32x16 output tile of one plane.
// grid = (NBX, NBY, 2*NPLANES); z < NPLANES -> x tensor, else y.
__global__ __launch_bounds__(256) void blur_hist(
        const float* __restrict__ x, const float* __restrict__ y,
        unsigned int* __restrict__ partial) {
    const int z = blockIdx.z;
    const float* src = (z < NPLANES) ? x + (size_t)z * H * W
                                     : y + (size_t)(z - NPLANES) * H * W;

    __shared__ __align__(16) float raw[TROWS * RP];  // 10.65 KB
    __shared__ float ve[TOY * VP];                   // even cols, vertically blurred
    __shared__ float vo[TOY * VP];                   // odd  cols, vertically blurred
    __shared__ unsigned int sh[NSH * BINS];          // 32 sub-histograms (3.2 KB)

    const int tid = threadIdx.x;
    const int base_x = 2 * (blockIdx.x * TOX) - 4;   // even
    const int base_y = 2 * (blockIdx.y * TOY) - 3;

    for (int i = tid; i < NSH * BINS; i += 256) sh[i] = 0u;

    // ---- Stage 1: global -> LDS ----
    const bool interior = (base_x >= 0) && (base_x + RP <= W) &&
                          (base_y >= 0) && (base_y + TROWS <= H);
    if (interior) {
        // async direct-to-LDS, 16B/lane; pitch 72 floats = 18 lanes -> rows contiguous
        #pragma unroll
        for (int k = 0; k < 3; k++) {
            int v = 256 * k + tid;
            if (v < NV4) {
                int r = v / 18;
                int c = v - r * 18;
                const float* g = src + (size_t)(base_y + r) * W + base_x + 4 * c;
                float* dst = raw + (size_t)(256 * k + (tid & ~63)) * 4;
                async_load16(g, dst);
            }
        }
    } else {
        const bool xfull = (base_x >= 0) && (base_x + RP <= W);
        for (int v = tid; v < NV4; v += 256) {
            int r  = v / 18;
            int c4 = v - r * 18;
            int gy = base_y + r;
            int gx = base_x + 4 * c4;
            float4 val = make_float4(0.f, 0.f, 0.f, 0.f);
            if (gy >= 0 && gy < H) {
                if (xfull) {
                    val = *(const float4*)(src + (size_t)gy * W + gx);
                } else {
                    const size_t rb = (size_t)gy * W;
                    if (gx + 0 >= 0 && gx + 0 < W) val.x = src[rb + gx + 0];
                    if (gx + 1 >= 0 && gx + 1 < W) val.y = src[rb + gx + 1];
                    if (gx + 2 >= 0 && gx + 2 < W) val.z = src[rb + gx + 2];
                    if (gx + 3 >= 0 && gx + 3 < W) val.w = src[rb + gx + 3];
                }
            }
            *(float4*)(raw + r * RP + 4 * c4) = val;
        }
    }
    __syncthreads();   // drains vmcnt for async loads

    const float w0 = 1.f/64.f, w1 = 6.f/64.f, w2 = 15.f/64.f, w3 = 20.f/64.f;

    // ---- Stage 2: vertical 7-tap (stride 2 in y). Scalar b32 reads, lanes
    //      consecutive in t (2-way = free). De-interleave into ve/vo via
    //      predicated writes (each half-populated instruction conflict-free). ----
    for (int v = tid; v < TOY * 70; v += 256) {
        int ly = v / 70;
        int t  = v - ly * 70;
        const float* p = raw + (2 * ly) * RP + t;
        float s = w0 * (p[0] + p[6 * RP]) + w1 * (p[1 * RP] + p[5 * RP])
                + w2 * (p[2 * RP] + p[4 * RP]) + w3 * p[3 * RP];
        int pr = t >> 1;
        if (t & 1) vo[ly * VP + pr] = s;
        else       ve[ly * VP + pr] = s;
    }
    __syncthreads();

    // ---- Stage 3: horizontal 7-tap (stride 2 in x), stride-1 reads + hist.
    //      32 sub-hists: same-address atomic multiplicity ~2 instead of ~14. ----
    const int lx = tid & 31;
    unsigned int* wh = sh + (tid & 31) * BINS;
    #pragma unroll
    for (int i = 0; i < 2; i++) {
        int ly = (tid >> 5) + 8 * i;
        const float* e = ve + ly * VP + lx;
        const float* o = vo + ly * VP + lx;
        float s = w0*(o[0] + o[3]) + w2*(o[1] + o[2]) + w1*(e[1] + e[3]) + w3*e[2];
        int b = min((int)(s * 25.f), BINS - 1);   // s in [0,1] by construction
        atomicAdd(&wh[b], 1u);
    }
    __syncthreads();

    // ---- Per-block histogram write-out ----
    if (tid < BINS) {
        unsigned int s = 0;
        #pragma unroll
        for (int g = 0; g < NSH; g++) s += sh[g * BINS + tid];
        int blk = blockIdx.y * NBX + blockIdx.x;
        partial[((size_t)z * NBLK + blk) * BINS + tid] = s;
    }
}

// 96 blocks x 256 threads: block p reduces plane p's partials for x and y,
// computes cosine sim, atomically accumulates mean into out[0].
__global__ __launch_bounds__(256) void reduce_cos(
        const unsigned int* __restrict__ partial, float* __restrict__ out) {
    __shared__ unsigned int sh[2 * BINS];
    const int p = blockIdx.x;
    const int t = threadIdx.x;
    if (t < 2 * BINS) sh[t] = 0u;
    __syncthreads();
    const unsigned int* xp = partial + (size_t)p * NBLK * BINS;
    const unsigned int* yp = partial + (size_t)(NPLANES + p) * NBLK * BINS;
    for (int f = t; f < NBLK * BINS; f += 256) {
        int b = f % BINS;
        atomicAdd(&sh[b], xp[f]);
        atomicAdd(&sh[BINS + b], yp[f]);
    }
    __syncthreads();
    if (t == 0) {
        const float inv_hw = 1.0f / (float)(H * W);
        float dot = 0.f, nx = 0.f, ny = 0.f;
        for (int i = 0; i < BINS; i++) {
            float a = (float)sh[i] * inv_hw;
            float b = (float)sh[BINS + i] * inv_hw;
            dot += a * b;
            nx  += a * a;
            ny  += b * b;
        }
        nx = fmaxf(sqrtf(nx), 1e-6f);
        ny = fmaxf(sqrtf(ny), 1e-6f);
        atomicAdd(out, (dot / (nx * ny)) * (1.0f / (float)NPLANES));
    }
}

extern "C" void kernel_launch(void* const* d_in, const int* in_sizes, int n_in,
                              void* d_out, int out_size, void* d_ws, size_t ws_size,
                              hipStream_t stream) {
    const float* x = (const float*)d_in[0];
    const float* y = (const float*)d_in[1];
    float* out = (float*)d_out;

    // partial hists: [2*NPLANES][NBLK][BINS] uint = 2.46 MB in ws.
    unsigned int* partial = (unsigned int*)d_ws;

    hipMemsetAsync(out, 0, sizeof(float), stream);

    dim3 grd(NBX, NBY, 2 * NPLANES);
    blur_hist<<<grd, 256, 0, stream>>>(x, y, partial);

    reduce_cos<<<NPLANES, 256, 0, stream>>>(partial, out);
}

// Round 5
// 229.837 us; speedup vs baseline: 2.2623x; 1.0075x over previous
//
#include <hip/hip_runtime.h>

#define BINS 25
#define H 512
#define W 512
#define NPLANES 96   // B*C = 32*3
#define TOX 32       // output tile width
#define TOY 16       // output tile height
#define NBX 8        // OW/TOX
#define NBY 16       // OH/TOY
#define NBLK (NBX*NBY)   // 128 tiles per plane
#define TROWS 37     // input rows: 2*16+5
#define RP 72        // raw pitch (floats) = 18 float4
#define NV4 (TROWS*18)   // 666 float4 loads per tile
#define VP 36        // ve/vo pitch (floats, multiple of 4)
#define NSH 16       // sub-histograms per block

__device__ __forceinline__ void async_load16(const float* g, float* lds_wave_base) {
    __builtin_amdgcn_global_load_lds(
        (const __attribute__((address_space(1))) void*)g,
        (__attribute__((address_space(3))) void*)lds_wave_base,
        16, 0, 0);
}

// Block = 256 threads, one 32x16 output tile of one plane.
// grid = (NBX, NBY, 2*NPLANES); z < NPLANES -> x tensor, else y.
__global__ __launch_bounds__(256) void blur_hist(
        const float* __restrict__ x, const float* __restrict__ y,
        unsigned int* __restrict__ partial) {
    const int z = blockIdx.z;
    const float* src = (z < NPLANES) ? x + (size_t)z * H * W
                                     : y + (size_t)(z - NPLANES) * H * W;

    __shared__ __align__(16) float raw[TROWS * RP];      // 10.65 KB
    __shared__ __align__(16) float ve[TOY * VP];         // even cols, vert-blurred
    __shared__ __align__(16) float vo[TOY * VP];         // odd  cols, vert-blurred
    __shared__ __align__(16) unsigned int sh[NSH * BINS];// 16 sub-hists (1.6 KB)

    const int tid = threadIdx.x;
    const int base_x = 2 * (blockIdx.x * TOX) - 4;   // even
    const int base_y = 2 * (blockIdx.y * TOY) - 3;

    if (tid < 100) {   // zero 400 words with wave-wide float4 stores
        float4 z4 = make_float4(0.f, 0.f, 0.f, 0.f);
        *(float4*)((float*)sh + 4 * tid) = z4;
    }

    // ---- Stage 1: global -> LDS ----
    const bool interior = (base_x >= 0) && (base_x + RP <= W) &&
                          (base_y >= 0) && (base_y + TROWS <= H);
    if (interior) {
        #pragma unroll
        for (int k = 0; k < 3; k++) {
            int v = 256 * k + tid;
            if (v < NV4) {
                int r = v / 18;
                int c = v - r * 18;
                const float* g = src + (size_t)(base_y + r) * W + base_x + 4 * c;
                float* dst = raw + (size_t)(256 * k + (tid & ~63)) * 4;
                async_load16(g, dst);
            }
        }
    } else {
        const bool xfull = (base_x >= 0) && (base_x + RP <= W);
        for (int v = tid; v < NV4; v += 256) {
            int r  = v / 18;
            int c4 = v - r * 18;
            int gy = base_y + r;
            int gx = base_x + 4 * c4;
            float4 val = make_float4(0.f, 0.f, 0.f, 0.f);
            if (gy >= 0 && gy < H) {
                if (xfull) {
                    val = *(const float4*)(src + (size_t)gy * W + gx);
                } else {
                    const size_t rb = (size_t)gy * W;
                    if (gx + 0 >= 0 && gx + 0 < W) val.x = src[rb + gx + 0];
                    if (gx + 1 >= 0 && gx + 1 < W) val.y = src[rb + gx + 1];
                    if (gx + 2 >= 0 && gx + 2 < W) val.z = src[rb + gx + 2];
                    if (gx + 3 >= 0 && gx + 3 < W) val.w = src[rb + gx + 3];
                }
            }
            *(float4*)(raw + r * RP + 4 * c4) = val;
        }
    }
    __syncthreads();   // drains vmcnt for async loads

    const float w0 = 1.f/64.f, w1 = 6.f/64.f, w2 = 15.f/64.f, w3 = 20.f/64.f;

    // ---- Stage 2: vertical 7-tap (stride 2 in y), 4 consecutive cols/thread
    //      via aligned ds_read_b128; de-interleave via aligned float2 writes. ----
    // tasks: 18 col-quads x 16 rows = 288
    for (int v = tid; v < TOY * 18; v += 256) {
        int ly = v / 18;
        int q  = v - ly * 18;
        const float* p = raw + (2 * ly) * RP + 4 * q;
        float4 a0 = *(const float4*)(p + 0 * RP);
        float4 a1 = *(const float4*)(p + 1 * RP);
        float4 a2 = *(const float4*)(p + 2 * RP);
        float4 a3 = *(const float4*)(p + 3 * RP);
        float4 a4 = *(const float4*)(p + 4 * RP);
        float4 a5 = *(const float4*)(p + 5 * RP);
        float4 a6 = *(const float4*)(p + 6 * RP);
        float s0 = w0*(a0.x+a6.x) + w1*(a1.x+a5.x) + w2*(a2.x+a4.x) + w3*a3.x;
        float s1 = w0*(a0.y+a6.y) + w1*(a1.y+a5.y) + w2*(a2.y+a4.y) + w3*a3.y;
        float s2 = w0*(a0.z+a6.z) + w1*(a1.z+a5.z) + w2*(a2.z+a4.z) + w3*a3.z;
        float s3 = w0*(a0.w+a6.w) + w1*(a1.w+a5.w) + w2*(a2.w+a4.w) + w3*a3.w;
        // t = 4q..4q+3 -> even t: pr = 2q, 2q+1 ; odd t: pr = 2q, 2q+1
        *(float2*)(ve + ly * VP + 2 * q) = make_float2(s0, s2);
        *(float2*)(vo + ly * VP + 2 * q) = make_float2(s1, s3);
    }
    __syncthreads();

    // ---- Stage 3: horizontal 7-tap (stride 2 in x), 4 consecutive outputs per
    //      thread from 4 aligned ds_read_b128; 128 active threads. ----
    if (tid < 128) {
        const int ly = tid >> 3;       // 0..15
        const int qq = tid & 7;        // 0..7 -> outputs lx = 4qq..4qq+3
        const float* ob = vo + ly * VP + 4 * qq;
        const float* eb = ve + ly * VP + 4 * qq;
        float4 A = *(const float4*)(ob);
        float4 B = *(const float4*)(ob + 4);
        float4 C = *(const float4*)(eb);
        float4 D = *(const float4*)(eb + 4);
        float oa[8] = {A.x, A.y, A.z, A.w, B.x, B.y, B.z, B.w};
        float ea[8] = {C.x, C.y, C.z, C.w, D.x, D.y, D.z, D.w};
        unsigned int* wh = sh + (tid & (NSH - 1)) * BINS;
        #pragma unroll
        for (int j = 0; j < 4; j++) {
            // out(lx=4qq+j) = w0*(o[j]+o[j+3]) + w2*(o[j+1]+o[j+2])
            //               + w1*(e[j+1]+e[j+3]) + w3*e[j+2]
            float s = w0*(oa[j] + oa[j+3]) + w2*(oa[j+1] + oa[j+2])
                    + w1*(ea[j+1] + ea[j+3]) + w3*ea[j+2];
            int b = min((int)(s * 25.f), BINS - 1);   // s in [0,1] by construction
            atomicAdd(&wh[b], 1u);
        }
    }
    __syncthreads();

    // ---- Per-block histogram write-out ----
    if (tid < BINS) {
        unsigned int s = 0;
        #pragma unroll
        for (int g = 0; g < NSH; g++) s += sh[g * BINS + tid];
        int blk = blockIdx.y * NBX + blockIdx.x;
        partial[((size_t)z * NBLK + blk) * BINS + tid] = s;
    }
}

// 96 blocks x 256 threads: block p reduces plane p's partials for x and y,
// computes cosine sim, atomically accumulates mean into out[0].
__global__ __launch_bounds__(256) void reduce_cos(
        const unsigned int* __restrict__ partial, float* __restrict__ out) {
    __shared__ unsigned int sh[2 * BINS];
    const int p = blockIdx.x;
    const int t = threadIdx.x;
    if (t < 2 * BINS) sh[t] = 0u;
    __syncthreads();
    const unsigned int* xp = partial + (size_t)p * NBLK * BINS;
    const unsigned int* yp = partial + (size_t)(NPLANES + p) * NBLK * BINS;
    for (int f = t; f < NBLK * BINS; f += 256) {
        int b = f % BINS;
        atomicAdd(&sh[b], xp[f]);
        atomicAdd(&sh[BINS + b], yp[f]);
    }
    __syncthreads();
    if (t == 0) {
        const float inv_hw = 1.0f / (float)(H * W);
        float dot = 0.f, nx = 0.f, ny = 0.f;
        for (int i = 0; i < BINS; i++) {
            float a = (float)sh[i] * inv_hw;
            float b = (float)sh[BINS + i] * inv_hw;
            dot += a * b;
            nx  += a * a;
            ny  += b * b;
        }
        nx = fmaxf(sqrtf(nx), 1e-6f);
        ny = fmaxf(sqrtf(ny), 1e-6f);
        atomicAdd(out, (dot / (nx * ny)) * (1.0f / (float)NPLANES));
    }
}

extern "C" void kernel_launch(void* const* d_in, const int* in_sizes, int n_in,
                              void* d_out, int out_size, void* d_ws, size_t ws_size,
                              hipStream_t stream) {
    const float* x = (const float*)d_in[0];
    const float* y = (const float*)d_in[1];
    float* out = (float*)d_out;

    unsigned int* partial = (unsigned int*)d_ws;   // [2*NPLANES][NBLK][BINS] = 2.46 MB

    hipMemsetAsync(out, 0, sizeof(float), stream);

    dim3 grd(NBX, NBY, 2 * NPLANES);
    blur_hist<<<grd, 256, 0, stream>>>(x, y, partial);

    reduce_cos<<<NPLANES, 256, 0, stream>>>(partial, out);
}